// Round 10
// baseline (17872.452 us; speedup 1.0000x reference)
//
#include <hip/hip_runtime.h>
#include <cstdint>
#include <cstddef>

#define BB 32
#define SS 512
#define HH 512
#define NBD 64      // blocks per direction
#define JPB 8       // j columns per block
#define WR 32       // W rows per block (4 gates * JPB)
#define WST 520     // Whh LDS row stride (bf16 elems)
#define HST 520     // h LDS row stride (bf16 elems)

typedef short v8s __attribute__((ext_vector_type(8)));
typedef float v4f __attribute__((ext_vector_type(4)));
typedef unsigned long long u64t;

static __device__ __forceinline__ float b2f(unsigned short u) {
    union { unsigned int i; float f; } v; v.i = ((unsigned int)u) << 16; return v.f;
}
static __device__ __forceinline__ unsigned short f2b(float f) {
    union { float f; unsigned int i; } v; v.f = f;
    unsigned int u = v.i;
    return (unsigned short)((u + 0x7fffu + ((u >> 16) & 1u)) >> 16);  // RNE
}
static __device__ __forceinline__ void split1(float f, short& hi, short& lo) {
    const unsigned short h = f2b(f);
    hi = (short)h;
    lo = (short)f2b(f - b2f(h));   // exact residual, then RNE
}
static __device__ __forceinline__ void split8(const float* __restrict__ p, v8s& hi, v8s& lo) {
    #pragma unroll
    for (int e = 0; e < 8; ++e) { short h, l; split1(p[e], h, l); hi[e] = h; lo[e] = l; }
}

#define MFMA(a, b, c) __builtin_amdgcn_mfma_f32_16x16x32_bf16((a), (b), (c), 0, 0, 0)

// One bidirectional layer; persistent blocks.
// r10 sync: TAGGED h-packets fuse flag+data into ONE coherent round trip.
// Packet u64 = {h0hi, h0lo, h1hi, h1lo} bf16-split pair; LSB of each lo word
// carries a 2-bit step tag (st+1)&3. Producer: 128 relaxed agent stores, NO
// drain/barrier/flag, proceeds immediately. Consumer: polls its 32 packets
// until tags match st&3 (re-polling only stale ones). Mod-4 tags + max-lag-1
// (each poll gates on all producers) + L3 serialization make stale/init/
// prev-call data always rejected or bit-identical. lo-LSB steal costs
// <= h*2^-16 (split precision), within threshold margin.
template<int DIN, bool L0>
__global__ __launch_bounds__(256, 1)
void lstm_layer(const void*  __restrict__ xin_,
                const float* __restrict__ Wih_f,  // [4H, DIN] f32
                const float* __restrict__ Whh_f,  // [4H, H]  f32
                const float* __restrict__ b_f,    // [4H]     f32
                const float* __restrict__ Wih_b,
                const float* __restrict__ Whh_b,
                const float* __restrict__ b_b,
                void*  __restrict__ yout_,         // L0: bf16 [B,S,2H]; L1: f32 [B,S,2H]
                u64t*  __restrict__ hrec,          // [2dir][2par][B][H/2] tagged packets
                float* __restrict__ hn,            // [2][B][H] f32 (L1) or nullptr
                float* __restrict__ cn)            // [2][B][H] f32 (L1) or nullptr
{
    constexpr int NKX = DIN / 32;
    constexpr int NKH = HH / 32;

    extern __shared__ char smem[];
    unsigned short* WhhHi = (unsigned short*)smem;          // [32][WST]
    unsigned short* WhhLo = WhhHi + WR * WST;               // [32][WST]
    unsigned short* hHi   = WhhLo + WR * WST;               // [32][HST] batch-major
    unsigned short* hLo   = hHi + BB * HST;                 // [32][HST]
    float* gatesl = (float*)(hLo + BB * HST);               // [32][36]
    float* biasl  = gatesl + 32 * 36;

    const int tid   = threadIdx.x;
    const int dir   = blockIdx.x >> 6;
    const int jb    = blockIdx.x & 63;
    const int jbase = jb * JPB;

    const float* Wih = dir ? Wih_b : Wih_f;
    const float* Whh = dir ? Whh_b : Whh_f;
    const float* bv  = dir ? b_b  : b_f;

    // ---- stage Whh slice split hi/lo into LDS ----
    {
        const int r  = tid >> 3;
        const int c0 = (tid & 7) * 64;
        const int R  = (r >> 3) * HH + jbase + (r & 7);   // gate*512 + j
        const float* src = Whh + (size_t)R * HH + c0;
        #pragma unroll
        for (int c = 0; c < 64; c += 8) {
            v8s hi, lo; split8(src + c, hi, lo);
            *(v8s*)(WhhHi + r * WST + c0 + c) = hi;
            *(v8s*)(WhhLo + r * WST + c0 + c) = lo;
        }
    }
    if (tid < WR) biasl[tid] = bv[(tid >> 3) * HH + jbase + (tid & 7)];

    const int lane = tid & 63;
    const int wv   = tid >> 6;
    const int mi   = wv & 1;         // M-frag (batch half)
    const int ni   = wv >> 1;        // N-frag (gate-row half)
    const int g    = lane >> 4;      // k-group
    const int rA   = lane & 15;

    const int brow = mi * 16 + rA;   // batch row (A-frag)
    const int nrow = ni * 16 + rA;   // local gate-row (B-frag)
    const int Rn   = (nrow >> 3) * HH + jbase + (nrow & 7);

    // ---- Wih B-fragments split hi/lo into registers (static indexing) ----
    v8s wxh[NKX], wxl[NKX];
    {
        const float* src = Wih + (size_t)Rn * DIN + 8 * g;
        #pragma unroll
        for (int kt = 0; kt < NKX; ++kt) split8(src + kt * 32, wxh[kt], wxl[kt]);
    }
    __syncthreads();

    const float*          aXf = L0 ? (const float*)xin_ + (size_t)brow * SS * DIN + 8 * g : nullptr;
    const unsigned short* aXb = L0 ? nullptr : (const unsigned short*)xin_ + (size_t)brow * SS * DIN + 8 * g;
    const unsigned short* bHb = WhhHi + nrow * WST + 8 * g;
    const unsigned short* bLb = WhhLo + nrow * WST + 8 * g;

    const int eb = tid >> 3;         // epilogue: batch row
    const int ej = tid & 7;          // epilogue: local col
    float creg = 0.f;

    for (int st = 0; st < SS; ++st) {
        const int t = dir ? (SS - 1 - st) : st;

        v4f acc0 = {0,0,0,0}, acc1 = {0,0,0,0}, acc2 = {0,0,0,0};
        v4f acc3 = {0,0,0,0}, acc4 = {0,0,0,0}, acc5 = {0,0,0,0};

        // ---- x-part (pre-poll; covers peers' packet flight time) ----
        if (L0) {
            const float* aX = aXf + (size_t)t * DIN;
            #pragma unroll
            for (int kt = 0; kt < NKX; kt += 2) {
                v8s ah0, al0, ah1, al1;
                split8(aX + kt * 32, ah0, al0);
                split8(aX + (kt + 1) * 32, ah1, al1);
                acc0 = MFMA(ah0, wxh[kt],     acc0);
                acc1 = MFMA(ah1, wxh[kt + 1], acc1);
                acc2 = MFMA(ah0, wxl[kt],     acc2);
                acc3 = MFMA(ah1, wxl[kt + 1], acc3);
                acc4 = MFMA(al0, wxh[kt],     acc4);
                acc5 = MFMA(al1, wxh[kt + 1], acc5);
            }
        } else {
            const unsigned short* aX = aXb + (size_t)t * DIN;
            #pragma unroll
            for (int kt = 0; kt < NKX; kt += 2) {
                v8s a0 = *(const v8s*)(aX + kt * 32);
                v8s a1 = *(const v8s*)(aX + (kt + 1) * 32);
                acc0 = MFMA(a0, wxh[kt],     acc0);
                acc1 = MFMA(a1, wxh[kt + 1], acc1);
                acc2 = MFMA(a0, wxl[kt],     acc2);
                acc3 = MFMA(a1, wxl[kt + 1], acc3);
            }
        }

        // ---- poll tagged h packets; stage into LDS; h-part ----
        if (st > 0) {
            const u64t* hsrc = hrec + (size_t)(dir * 2 + ((st - 1) & 1)) * (BB * HH / 2);
            const unsigned expect = (unsigned)(st & 3);   // TAG(st-1)
            u64t vals[32];
            unsigned pend = 0xffffffffu;
            int guard = 0;
            while (pend) {
                #pragma unroll
                for (int k = 0; k < 32; ++k) {
                    if (pend & (1u << k)) {
                        const u64t v = __hip_atomic_load(hsrc + (size_t)k * 256 + tid,
                                           __ATOMIC_RELAXED, __HIP_MEMORY_SCOPE_AGENT);
                        const unsigned tgv = ((unsigned)(v >> 16) & 1u)
                                           | (((unsigned)(v >> 48) & 1u) << 1);
                        if (tgv == expect) { vals[k] = v; pend &= ~(1u << k); }
                    }
                }
                if (++guard > (1 << 16)) break;   // anti-hang escape (bug-only)
            }
            // unpack packets straight into hi/lo LDS planes (split already done)
            #pragma unroll
            for (int k = 0; k < 32; ++k) {
                const u64t v = vals[k];
                const unsigned hiw = (unsigned)(v & 0xffffu)
                                   | (((unsigned)((v >> 32) & 0xffffu)) << 16);
                const unsigned low = (unsigned)((v >> 16) & 0xffffu)
                                   | (((unsigned)(v >> 48)) << 16);
                *(unsigned*)(hHi + k * HST + 2 * tid) = hiw;
                *(unsigned*)(hLo + k * HST + 2 * tid) = low;
            }
            __syncthreads();

            const unsigned short* aHh = hHi + brow * HST + 8 * g;
            const unsigned short* aHl = hLo + brow * HST + 8 * g;
            #pragma unroll
            for (int kt = 0; kt < NKH; kt += 2) {
                v8s ah0 = *(const v8s*)(aHh + kt * 32);
                v8s al0 = *(const v8s*)(aHl + kt * 32);
                v8s ah1 = *(const v8s*)(aHh + (kt + 1) * 32);
                v8s al1 = *(const v8s*)(aHl + (kt + 1) * 32);
                v8s bh0 = *(const v8s*)(bHb + kt * 32);
                v8s bl0 = *(const v8s*)(bLb + kt * 32);
                v8s bh1 = *(const v8s*)(bHb + (kt + 1) * 32);
                v8s bl1 = *(const v8s*)(bLb + (kt + 1) * 32);
                acc0 = MFMA(ah0, bh0, acc0);
                acc1 = MFMA(ah1, bh1, acc1);
                acc2 = MFMA(ah0, bl0, acc2);
                acc3 = MFMA(ah1, bl1, acc3);
                acc4 = MFMA(al0, bh0, acc4);
                acc5 = MFMA(al1, bh1, acc5);
            }
        }
        acc0 = ((acc0 + acc1) + (acc2 + acc3)) + (acc4 + acc5);

        // ---- exchange gate preacts via LDS (C/D m89, probe-confirmed r4) ----
        {
            const int gb = mi * 16 + 4 * g;
            const int gw = ni * 16 + rA;
            gatesl[(gb + 0) * 36 + gw] = acc0[0];
            gatesl[(gb + 1) * 36 + gw] = acc0[1];
            gatesl[(gb + 2) * 36 + gw] = acc0[2];
            gatesl[(gb + 3) * 36 + gw] = acc0[3];
        }
        __syncthreads();

        // ---- gates (torch order i,f,g,o) + state update + tagged publish ----
        {
            const float pi = gatesl[eb * 36 +      ej] + biasl[     ej];
            const float pf = gatesl[eb * 36 +  8 + ej] + biasl[ 8 + ej];
            const float pg = gatesl[eb * 36 + 16 + ej] + biasl[16 + ej];
            const float po = gatesl[eb * 36 + 24 + ej] + biasl[24 + ej];
            const float ig = 1.f / (1.f + __expf(-pi));
            const float fg = 1.f / (1.f + __expf(-pf));
            const float gg = tanhf(pg);
            const float og = 1.f / (1.f + __expf(-po));
            creg = fg * creg + ig * gg;
            const float h = og * tanhf(creg);
            const float hp = __shfl_xor(h, 1);

            // tagged packet publish: ONE relaxed store, nothing else on the path
            if ((ej & 1) == 0) {
                const unsigned tg = (unsigned)((st + 1) & 3);
                short h0h, h0l, h1h, h1l;
                split1(h,  h0h, h0l);
                split1(hp, h1h, h1l);
                const unsigned uh0l = ((unsigned)(unsigned short)h0l & ~1u) | (tg & 1u);
                const unsigned uh1l = ((unsigned)(unsigned short)h1l & ~1u) | ((tg >> 1) & 1u);
                const u64t pk = (u64t)(unsigned short)h0h
                              | ((u64t)uh0l << 16)
                              | ((u64t)(unsigned short)h1h << 32)
                              | ((u64t)uh1l << 48);
                u64t* hw = hrec + (size_t)(dir * 2 + (st & 1)) * (BB * HH / 2)
                         + eb * 256 + ((jbase + ej) >> 1);
                __hip_atomic_store(hw, pk, __ATOMIC_RELAXED, __HIP_MEMORY_SCOPE_AGENT);
            }

            // y output: plain cached stores, fully off the inter-block path
            if (L0) {
                if ((ej & 1) == 0) {
                    const unsigned int pko = (unsigned int)f2b(h)
                                           | ((unsigned int)f2b(hp) << 16);
                    *((unsigned int*)yout_ + (size_t)eb * SS * HH + (size_t)t * HH
                                           + dir * (HH / 2) + ((jbase + ej) >> 1)) = pko;
                }
            } else {
                ((float*)yout_)[((size_t)eb * SS + t) * (2 * HH) + dir * HH + jbase + ej] = h;
                if (st == SS - 1) {
                    hn[(dir * BB + eb) * HH + jbase + ej] = h;
                    cn[(dir * BB + eb) * HH + jbase + ej] = creg;
                }
            }
        }
    }
}

extern "C" void kernel_launch(void* const* d_in, const int* in_sizes, int n_in,
                              void* d_out, int out_size, void* d_ws, size_t ws_size,
                              hipStream_t stream) {
    (void)in_sizes; (void)n_in;

    const float* x      = (const float*)d_in[0];
    const float* Wih_f0 = (const float*)d_in[1];
    const float* Whh_f0 = (const float*)d_in[2];
    const float* b_f0   = (const float*)d_in[3];
    const float* Wih_b0 = (const float*)d_in[4];
    const float* Whh_b0 = (const float*)d_in[5];
    const float* b_b0   = (const float*)d_in[6];
    const float* Wih_f1 = (const float*)d_in[7];
    const float* Whh_f1 = (const float*)d_in[8];
    const float* b_f1   = (const float*)d_in[9];
    const float* Wih_b1 = (const float*)d_in[10];
    const float* Whh_b1 = (const float*)d_in[11];
    const float* b_b1   = (const float*)d_in[12];

    // ws: [0,32Mi) y0 bf16 [B,S,2H]; +512K hrec0; +512K hrec1 (tagged packets)
    char* ws = (char*)d_ws;
    const size_t Y0B  = (size_t)BB * SS * 2 * HH * 2;             // 33,554,432
    const size_t HREC = (size_t)2 * 2 * BB * HH * 4;              // 524,288 each
    const size_t NEED = Y0B + 2 * HREC;                           // 34,603,008 (= r9 NEED)
    if (ws_size < NEED) return;
    if ((size_t)out_size < (size_t)BB * SS * 2 * HH + 4 * BB * HH) return;

    unsigned short* y0    = (unsigned short*)(ws);
    u64t*           hrec0 = (u64t*)(ws + Y0B);
    u64t*           hrec1 = (u64t*)(ws + Y0B + HREC);

    float* out = (float*)d_out;                          // [B,S,2H] f32
    float* hn  = out + (size_t)BB * SS * 2 * HH;         // [2,B,H]
    float* cn  = hn + 2 * BB * HH;                       // [2,B,H]

    // zero hrec: tag bits read 0 -> first polls (expect tags 1,2) always reject init
    hipMemsetAsync(ws + Y0B, 0, 2 * HREC, stream);

    // LDS: Whh hi/lo + h hi/lo + gates + bias
    constexpr int SMB = 2 * WR * WST * 2 + 2 * BB * HST * 2 + 32 * 36 * 4 + 128;  // 137,984
    hipFuncSetAttribute(reinterpret_cast<const void*>(lstm_layer<512,  true>),
                        hipFuncAttributeMaxDynamicSharedMemorySize, SMB);
    hipFuncSetAttribute(reinterpret_cast<const void*>(lstm_layer<1024, false>),
                        hipFuncAttributeMaxDynamicSharedMemorySize, SMB);

    lstm_layer<512, true><<<128, 256, SMB, stream>>>(
        x, Wih_f0, Whh_f0, b_f0, Wih_b0, Whh_b0, b_b0,
        (void*)y0, hrec0, nullptr, nullptr);

    lstm_layer<1024, false><<<128, 256, SMB, stream>>>(
        y0, Wih_f1, Whh_f1, b_f1, Wih_b1, Whh_b1, b_b1,
        (void*)out, hrec1, hn, cn);
}

// Round 11
// 9820.335 us; speedup vs baseline: 1.8199x; 1.8199x over previous
//
#include <hip/hip_runtime.h>
#include <cstdint>
#include <cstddef>

#define BB 32
#define SS 512
#define HH 512
#define NBD 64      // blocks per direction
#define JPB 8       // j columns per block
#define WR 32       // W rows per block (4 gates * JPB)
#define WST 520     // Whh LDS row stride (bf16 elems)
#define HST 520     // h LDS row stride (bf16 elems)

typedef short v8s __attribute__((ext_vector_type(8)));
typedef float v4f __attribute__((ext_vector_type(4)));
typedef unsigned long long u64t;

static __device__ __forceinline__ float b2f(unsigned short u) {
    union { unsigned int i; float f; } v; v.i = ((unsigned int)u) << 16; return v.f;
}
static __device__ __forceinline__ unsigned short f2b(float f) {
    union { float f; unsigned int i; } v; v.f = f;
    unsigned int u = v.i;
    return (unsigned short)((u + 0x7fffu + ((u >> 16) & 1u)) >> 16);  // RNE
}
static __device__ __forceinline__ void split1(float f, short& hi, short& lo) {
    const unsigned short h = f2b(f);
    hi = (short)h;
    lo = (short)f2b(f - b2f(h));   // exact residual, then RNE
}
static __device__ __forceinline__ void split8(const float* __restrict__ p, v8s& hi, v8s& lo) {
    #pragma unroll
    for (int e = 0; e < 8; ++e) { short h, l; split1(p[e], h, l); hi[e] = h; lo[e] = l; }
}

#define MFMA(a, b, c) __builtin_amdgcn_mfma_f32_16x16x32_bf16((a), (b), (c), 0, 0, 0)

// One bidirectional layer; persistent blocks, per-timestep producer flags.
// r11 (on proven r9 base; r10 tagged-packet design reverted — data-polling
// storm regressed 1.8x):
//  (1) W rows reordered so LDS row c = (gate c&3, j c>>2): the 4 gate preacts
//      of each (batch, j) land in 4 adjacent lanes -> 6-shfl in-wave 4x4
//      transpose replaces the gates-LDS exchange (one fewer barrier, earlier
//      publish).
//  (2) fused poll+stage: staging thread tid's h-columns come from exactly one
//      producer (jb = tid>>2); thread polls that flag only, then loads+stages
//      its 32 u64s immediately -> straggler tail overlapped, post-poll
//      barrier removed (prev publish barrier guarantees LDS write safety).
// Numerics identical to r7-r9 (split-bf16 everywhere, f32 h-exchange).
template<int DIN, bool L0>
__global__ __launch_bounds__(256, 1)
void lstm_layer(const void*  __restrict__ xin_,
                const float* __restrict__ Wih_f,  // [4H, DIN] f32
                const float* __restrict__ Whh_f,  // [4H, H]  f32
                const float* __restrict__ b_f,    // [4H]     f32
                const float* __restrict__ Wih_b,
                const float* __restrict__ Whh_b,
                const float* __restrict__ b_b,
                void*  __restrict__ yout_,         // L0: bf16 [B,S,2H]; L1: f32 [B,S,2H]
                float* __restrict__ hrec,          // [2dir][2par][B][H] f32 exchange
                unsigned int* __restrict__ flags,  // [2dir][S][64], zeroed each call
                float* __restrict__ hn,            // [2][B][H] f32 (L1) or nullptr
                float* __restrict__ cn)            // [2][B][H] f32 (L1) or nullptr
{
    constexpr int NKX = DIN / 32;
    constexpr int NKH = HH / 32;

    extern __shared__ char smem[];
    unsigned short* WhhHi = (unsigned short*)smem;          // [32][WST] reordered rows
    unsigned short* WhhLo = WhhHi + WR * WST;               // [32][WST]
    unsigned short* hHi   = WhhLo + WR * WST;               // [32][HST] batch-major
    unsigned short* hLo   = hHi + BB * HST;                 // [32][HST]

    const int tid   = threadIdx.x;
    const int dir   = blockIdx.x >> 6;
    const int jb    = blockIdx.x & 63;
    const int jbase = jb * JPB;

    const float* Wih = dir ? Wih_b : Wih_f;
    const float* Whh = dir ? Whh_b : Whh_f;
    const float* bv  = dir ? b_b  : b_f;

    // ---- stage Whh slice split hi/lo into LDS (REORDERED: row r -> W row
    //      (r&3)*H + jbase + (r>>2), i.e. gate-in-low-2-bits) ----
    {
        const int r  = tid >> 3;
        const int c0 = (tid & 7) * 64;
        const int R  = (r & 3) * HH + jbase + (r >> 2);
        const float* src = Whh + (size_t)R * HH + c0;
        #pragma unroll
        for (int c = 0; c < 64; c += 8) {
            v8s hi, lo; split8(src + c, hi, lo);
            *(v8s*)(WhhHi + r * WST + c0 + c) = hi;
            *(v8s*)(WhhLo + r * WST + c0 + c) = lo;
        }
    }

    const int lane = tid & 63;
    const int wv   = tid >> 6;
    const int mi   = wv & 1;         // M-frag (batch half)
    const int ni   = wv >> 1;        // N-frag (gate-col half)
    const int g    = lane >> 4;      // k-group
    const int rA   = lane & 15;

    const int brow = mi * 16 + rA;   // batch row (A-frag)
    const int nrow = ni * 16 + rA;   // LDS B-frag row (= reordered col index)
    const int col  = ni * 16 + rA;   // this lane's output column c
    const int jl   = col >> 2;       // j within block (0..7)
    const int p    = rA & 3;         // lane pos in 4-lane gate subgroup

    // per-lane biases for j = jbase + jl (all 4 gates)
    const float bi_ = bv[0 * HH + jbase + jl];
    const float bf_ = bv[1 * HH + jbase + jl];
    const float bg_ = bv[2 * HH + jbase + jl];
    const float bo_ = bv[3 * HH + jbase + jl];

    // ---- Wih B-fragments split hi/lo into registers (reordered row) ----
    const int Rn = (col & 3) * HH + jbase + (col >> 2);
    v8s wxh[NKX], wxl[NKX];
    {
        const float* src = Wih + (size_t)Rn * DIN + 8 * g;
        #pragma unroll
        for (int kt = 0; kt < NKX; ++kt) split8(src + kt * 32, wxh[kt], wxl[kt]);
    }
    __syncthreads();

    const float*          aXf = L0 ? (const float*)xin_ + (size_t)brow * SS * DIN + 8 * g : nullptr;
    const unsigned short* aXb = L0 ? nullptr : (const unsigned short*)xin_ + (size_t)brow * SS * DIN + 8 * g;
    const unsigned short* bHb = WhhHi + nrow * WST + 8 * g;
    const unsigned short* bLb = WhhLo + nrow * WST + 8 * g;

    unsigned int* fbase = flags + (size_t)dir * SS * 64;   // per-direction flag plane

    const int batch = mi * 16 + 4 * g + p;   // this lane's epilogue batch
    float creg = 0.f;

    for (int st = 0; st < SS; ++st) {
        const int t = dir ? (SS - 1 - st) : st;

        v4f acc0 = {0,0,0,0}, acc1 = {0,0,0,0}, acc2 = {0,0,0,0};
        v4f acc3 = {0,0,0,0}, acc4 = {0,0,0,0}, acc5 = {0,0,0,0};

        // ---- x-part (pre-poll; covers peers' publish latency) ----
        if (L0) {
            const float* aX = aXf + (size_t)t * DIN;
            #pragma unroll
            for (int kt = 0; kt < NKX; kt += 2) {
                v8s ah0, al0, ah1, al1;
                split8(aX + kt * 32, ah0, al0);
                split8(aX + (kt + 1) * 32, ah1, al1);
                acc0 = MFMA(ah0, wxh[kt],     acc0);
                acc1 = MFMA(ah1, wxh[kt + 1], acc1);
                acc2 = MFMA(ah0, wxl[kt],     acc2);
                acc3 = MFMA(ah1, wxl[kt + 1], acc3);
                acc4 = MFMA(al0, wxh[kt],     acc4);
                acc5 = MFMA(al1, wxh[kt + 1], acc5);
            }
        } else {
            const unsigned short* aX = aXb + (size_t)t * DIN;
            #pragma unroll
            for (int kt = 0; kt < NKX; kt += 2) {
                v8s a0 = *(const v8s*)(aX + kt * 32);
                v8s a1 = *(const v8s*)(aX + (kt + 1) * 32);
                acc0 = MFMA(a0, wxh[kt],     acc0);
                acc1 = MFMA(a1, wxh[kt + 1], acc1);
                acc2 = MFMA(a0, wxl[kt],     acc2);
                acc3 = MFMA(a1, wxl[kt + 1], acc3);
            }
        }

        // ---- fused poll+stage: thread gates on ITS producer only ----
        if (st > 0) {
            {
                const unsigned int* f = fbase + (size_t)(st - 1) * 64 + (tid >> 2);
                int guard = 0;
                while (!__hip_atomic_load(f, __ATOMIC_RELAXED,
                                          __HIP_MEMORY_SCOPE_AGENT)) {
                    __builtin_amdgcn_s_sleep(1);
                    if (++guard > (1 << 26)) break;   // anti-hang escape
                }
            }
            // thread's columns (2tid, 2tid+1) across all 32 batch rows
            const u64t* hsrc = (const u64t*)hrec
                + ((size_t)(dir * 2 + ((st - 1) & 1)) * BB * HH) / 2;
            u64t vals[32];
            #pragma unroll
            for (int k = 0; k < 32; ++k)
                vals[k] = __hip_atomic_load(hsrc + (size_t)k * 256 + tid,
                                            __ATOMIC_RELAXED, __HIP_MEMORY_SCOPE_AGENT);
            #pragma unroll
            for (int k = 0; k < 32; ++k) {
                const float f0 = __uint_as_float((unsigned int)(vals[k] & 0xffffffffu));
                const float f1 = __uint_as_float((unsigned int)(vals[k] >> 32));
                short h0, l0, h1, l1;
                split1(f0, h0, l0);
                split1(f1, h1, l1);
                *(unsigned int*)(hHi + k * HST + 2 * tid) =
                    (unsigned int)(unsigned short)h0 | ((unsigned int)(unsigned short)h1 << 16);
                *(unsigned int*)(hLo + k * HST + 2 * tid) =
                    (unsigned int)(unsigned short)l0 | ((unsigned int)(unsigned short)l1 << 16);
            }
            __syncthreads();

            const unsigned short* aHh = hHi + brow * HST + 8 * g;
            const unsigned short* aHl = hLo + brow * HST + 8 * g;
            #pragma unroll
            for (int kt = 0; kt < NKH; kt += 2) {
                v8s ah0 = *(const v8s*)(aHh + kt * 32);
                v8s al0 = *(const v8s*)(aHl + kt * 32);
                v8s ah1 = *(const v8s*)(aHh + (kt + 1) * 32);
                v8s al1 = *(const v8s*)(aHl + (kt + 1) * 32);
                v8s bh0 = *(const v8s*)(bHb + kt * 32);
                v8s bl0 = *(const v8s*)(bLb + kt * 32);
                v8s bh1 = *(const v8s*)(bHb + (kt + 1) * 32);
                v8s bl1 = *(const v8s*)(bLb + (kt + 1) * 32);
                acc0 = MFMA(ah0, bh0, acc0);
                acc1 = MFMA(ah1, bh1, acc1);
                acc2 = MFMA(ah0, bl0, acc2);
                acc3 = MFMA(ah1, bl1, acc3);
                acc4 = MFMA(al0, bh0, acc4);
                acc5 = MFMA(al1, bh1, acc5);
            }
        }
        acc0 = ((acc0 + acc1) + (acc2 + acc3)) + (acc4 + acc5);

        // ---- in-wave 4x4 gate transpose (xor-1, xor-2 butterflies) ----
        // acc0[r] = preact(batch mi*16+4g+r, col) where col = (gate, j).
        // After transpose: lane p holds (i,f,g,o) for batch mi*16+4g+p, j=jl.
        float pi_, pf_, pg_, po_;
        {
            const float x0 = acc0[0], x1 = acc0[1], x2 = acc0[2], x3 = acc0[3];
            const float n0 = __shfl_xor(x0, 1), n1 = __shfl_xor(x1, 1);
            const float n2 = __shfl_xor(x2, 1), n3 = __shfl_xor(x3, 1);
            const float a0 = (p & 1) ? n1 : x0;
            const float a1 = (p & 1) ? x1 : n0;
            const float a2 = (p & 1) ? n3 : x2;
            const float a3 = (p & 1) ? x3 : n2;
            const float m0 = __shfl_xor(a0, 2), m1 = __shfl_xor(a1, 2);
            const float m2 = __shfl_xor(a2, 2), m3 = __shfl_xor(a3, 2);
            pi_ = (p & 2) ? m2 : a0;
            pf_ = (p & 2) ? m3 : a1;
            pg_ = (p & 2) ? a2 : m0;
            po_ = (p & 2) ? a3 : m1;
        }

        // ---- gates (torch order i,f,g,o) + state update + publish ----
        {
            const float ig = 1.f / (1.f + __expf(-(pi_ + bi_)));
            const float fg = 1.f / (1.f + __expf(-(pf_ + bf_)));
            const float gg = tanhf(pg_ + bg_);
            const float og = 1.f / (1.f + __expf(-(po_ + bo_)));
            creg = fg * creg + ig * gg;
            const float h = og * tanhf(creg);
            const float hq = __shfl_xor(h, 4);   // partner: same batch, jl^1

            // 1) h-exchange store (only store on the inter-block path)
            if ((jl & 1) == 0) {
                const u64t pk = ((u64t)__float_as_uint(hq) << 32)
                              | (u64t)__float_as_uint(h);
                u64t* hw = (u64t*)(hrec
                         + ((size_t)(dir * 2 + (st & 1))) * BB * HH
                         + (size_t)batch * HH + jbase + jl);
                __hip_atomic_store(hw, pk, __ATOMIC_RELAXED, __HIP_MEMORY_SCOPE_AGENT);
            }
            // 2) drain vmem, 3) block barrier, 4) flag
            asm volatile("s_waitcnt vmcnt(0)" ::: "memory");
            __syncthreads();
            if (tid == 0)
                __hip_atomic_store(fbase + (size_t)st * 64 + jb, 1u,
                                   __ATOMIC_RELAXED, __HIP_MEMORY_SCOPE_AGENT);

            // 5) y output stores AFTER the flag (drain under next step's x-part)
            if (L0) {
                if ((jl & 1) == 0) {
                    const unsigned int pko = (unsigned int)f2b(h)
                                           | ((unsigned int)f2b(hq) << 16);
                    *((unsigned int*)yout_ + (size_t)batch * SS * HH + (size_t)t * HH
                                           + dir * (HH / 2) + ((jbase + jl) >> 1)) = pko;
                }
            } else {
                ((float*)yout_)[((size_t)batch * SS + t) * (2 * HH) + dir * HH + jbase + jl] = h;
                if (st == SS - 1) {
                    hn[(dir * BB + batch) * HH + jbase + jl] = h;
                    cn[(dir * BB + batch) * HH + jbase + jl] = creg;
                }
            }
        }
    }
}

extern "C" void kernel_launch(void* const* d_in, const int* in_sizes, int n_in,
                              void* d_out, int out_size, void* d_ws, size_t ws_size,
                              hipStream_t stream) {
    (void)in_sizes; (void)n_in;

    const float* x      = (const float*)d_in[0];
    const float* Wih_f0 = (const float*)d_in[1];
    const float* Whh_f0 = (const float*)d_in[2];
    const float* b_f0   = (const float*)d_in[3];
    const float* Wih_b0 = (const float*)d_in[4];
    const float* Whh_b0 = (const float*)d_in[5];
    const float* b_b0   = (const float*)d_in[6];
    const float* Wih_f1 = (const float*)d_in[7];
    const float* Whh_f1 = (const float*)d_in[8];
    const float* b_f1   = (const float*)d_in[9];
    const float* Wih_b1 = (const float*)d_in[10];
    const float* Whh_b1 = (const float*)d_in[11];
    const float* b_b1   = (const float*)d_in[12];

    // ws: [0,32Mi) y0 bf16; +256K flags0[2][512][64]; +256K flags1; +512K hrec f32
    char* ws = (char*)d_ws;
    const size_t Y0B  = (size_t)BB * SS * 2 * HH * 2;             // 33,554,432
    const size_t FLG  = (size_t)2 * SS * 64 * 4;                  // 262,144 each
    const size_t HREC = (size_t)2 * 2 * BB * HH * 4;              // 524,288
    const size_t NEED = Y0B + 2 * FLG + HREC;
    if (ws_size < NEED) return;
    if ((size_t)out_size < (size_t)BB * SS * 2 * HH + 4 * BB * HH) return;

    unsigned short* y0     = (unsigned short*)(ws);
    unsigned int*   flags0 = (unsigned int*)(ws + Y0B);
    unsigned int*   flags1 = (unsigned int*)(ws + Y0B + FLG);
    float*          hrec   = (float*)(ws + Y0B + 2 * FLG);        // shared (sequential kernels)

    float* out = (float*)d_out;                          // [B,S,2H] f32
    float* hn  = out + (size_t)BB * SS * 2 * HH;         // [2,B,H]
    float* cn  = hn + 2 * BB * HH;                       // [2,B,H]

    hipMemsetAsync(ws + Y0B, 0, 2 * FLG, stream);        // zero flags each call

    // LDS: Whh hi/lo (66,560) + h hi/lo (66,560)
    constexpr int SMB = 2 * WR * WST * 2 + 2 * BB * HST * 2;      // 133,120
    hipFuncSetAttribute(reinterpret_cast<const void*>(lstm_layer<512,  true>),
                        hipFuncAttributeMaxDynamicSharedMemorySize, SMB);
    hipFuncSetAttribute(reinterpret_cast<const void*>(lstm_layer<1024, false>),
                        hipFuncAttributeMaxDynamicSharedMemorySize, SMB);

    lstm_layer<512, true><<<128, 256, SMB, stream>>>(
        x, Wih_f0, Whh_f0, b_f0, Wih_b0, Whh_b0, b_b0,
        (void*)y0, hrec, flags0, nullptr, nullptr);

    lstm_layer<1024, false><<<128, 256, SMB, stream>>>(
        y0, Wih_f1, Whh_f1, b_f1, Wih_b1, Whh_b1, b_b1,
        (void*)out, hrec, flags1, hn, cn);
}

// Round 12
// 7990.338 us; speedup vs baseline: 2.2368x; 1.2290x over previous
//
#include <hip/hip_runtime.h>
#include <cstdint>
#include <cstddef>

#define BB 32
#define SS 512
#define HH 512
#define NBD 64      // blocks per direction
#define JPB 8       // j columns per block
#define WR 32       // W rows per block (4 gates * JPB)
#define WST 520     // Whh LDS row stride (bf16 elems)
#define HST 520     // h LDS row stride (bf16 elems)

typedef short v8s __attribute__((ext_vector_type(8)));
typedef float v4f __attribute__((ext_vector_type(4)));
typedef unsigned long long u64t;

static __device__ __forceinline__ float b2f(unsigned short u) {
    union { unsigned int i; float f; } v; v.i = ((unsigned int)u) << 16; return v.f;
}
static __device__ __forceinline__ unsigned short f2b(float f) {
    union { float f; unsigned int i; } v; v.f = f;
    unsigned int u = v.i;
    return (unsigned short)((u + 0x7fffu + ((u >> 16) & 1u)) >> 16);  // RNE
}
static __device__ __forceinline__ void split1(float f, short& hi, short& lo) {
    const unsigned short h = f2b(f);
    hi = (short)h;
    lo = (short)f2b(f - b2f(h));   // exact residual, then RNE
}
static __device__ __forceinline__ void split8(const float* __restrict__ p, v8s& hi, v8s& lo) {
    #pragma unroll
    for (int e = 0; e < 8; ++e) { short h, l; split1(p[e], h, l); hi[e] = h; lo[e] = l; }
}

#define MFMA(a, b, c) __builtin_amdgcn_mfma_f32_16x16x32_bf16((a), (b), (c), 0, 0, 0)

// One bidirectional layer; persistent blocks, per-timestep producer flags.
// r12 (on r11): h-exchange carries bf16-HI only, packed 4/u64.
// Rationale: agent-atomic traffic is serviced at ~1 TB/s device-wide (fit of
// r8: 16MB/step->15.4us, r9/r11: 8MB->11us); halving exchange bytes is the
// lever. Weight hi/lo splits KEPT (systematic error); only the h-residual
// (a-lo) term of the recurrence GEMM is dropped -> fresh quantization noise
// ~2^-10|h|/step, predicted +1-2e-3 absmax. Consumer stages packed bf16
// DIRECTLY into the hHi LDS plane (no unpack VALU); hLo plane deleted.
template<int DIN, bool L0>
__global__ __launch_bounds__(256, 1)
void lstm_layer(const void*  __restrict__ xin_,
                const float* __restrict__ Wih_f,  // [4H, DIN] f32
                const float* __restrict__ Whh_f,  // [4H, H]  f32
                const float* __restrict__ b_f,    // [4H]     f32
                const float* __restrict__ Wih_b,
                const float* __restrict__ Whh_b,
                const float* __restrict__ b_b,
                void*  __restrict__ yout_,         // L0: bf16 [B,S,2H]; L1: f32 [B,S,2H]
                u64t*  __restrict__ hrec,          // [2dir][2par][B][H/4] bf16-hi x4 packed
                unsigned int* __restrict__ flags,  // [2dir][S][64], zeroed each call
                float* __restrict__ hn,            // [2][B][H] f32 (L1) or nullptr
                float* __restrict__ cn)            // [2][B][H] f32 (L1) or nullptr
{
    constexpr int NKX = DIN / 32;
    constexpr int NKH = HH / 32;

    extern __shared__ char smem[];
    unsigned short* WhhHi = (unsigned short*)smem;          // [32][WST] reordered rows
    unsigned short* WhhLo = WhhHi + WR * WST;               // [32][WST]
    unsigned short* hHi   = WhhLo + WR * WST;               // [32][HST] batch-major bf16-hi

    const int tid   = threadIdx.x;
    const int dir   = blockIdx.x >> 6;
    const int jb    = blockIdx.x & 63;
    const int jbase = jb * JPB;

    const float* Wih = dir ? Wih_b : Wih_f;
    const float* Whh = dir ? Whh_b : Whh_f;
    const float* bv  = dir ? b_b  : b_f;

    // ---- stage Whh slice split hi/lo into LDS (row r -> W row (r&3)*H + jbase + (r>>2)) ----
    {
        const int r  = tid >> 3;
        const int c0 = (tid & 7) * 64;
        const int R  = (r & 3) * HH + jbase + (r >> 2);
        const float* src = Whh + (size_t)R * HH + c0;
        #pragma unroll
        for (int c = 0; c < 64; c += 8) {
            v8s hi, lo; split8(src + c, hi, lo);
            *(v8s*)(WhhHi + r * WST + c0 + c) = hi;
            *(v8s*)(WhhLo + r * WST + c0 + c) = lo;
        }
    }

    const int lane = tid & 63;
    const int wv   = tid >> 6;
    const int mi   = wv & 1;         // M-frag (batch half)
    const int ni   = wv >> 1;        // N-frag (gate-col half)
    const int g    = lane >> 4;      // k-group
    const int rA   = lane & 15;

    const int brow = mi * 16 + rA;   // batch row (A-frag)
    const int nrow = ni * 16 + rA;   // LDS B-frag row (= reordered col index)
    const int col  = ni * 16 + rA;   // this lane's output column c
    const int jl   = col >> 2;       // j within block (0..7)
    const int p    = rA & 3;         // lane pos in 4-lane gate subgroup

    // per-lane biases for j = jbase + jl (all 4 gates)
    const float bi_ = bv[0 * HH + jbase + jl];
    const float bf_ = bv[1 * HH + jbase + jl];
    const float bg_ = bv[2 * HH + jbase + jl];
    const float bo_ = bv[3 * HH + jbase + jl];

    // ---- Wih B-fragments split hi/lo into registers (reordered row) ----
    const int Rn = (col & 3) * HH + jbase + (col >> 2);
    v8s wxh[NKX], wxl[NKX];
    {
        const float* src = Wih + (size_t)Rn * DIN + 8 * g;
        #pragma unroll
        for (int kt = 0; kt < NKX; ++kt) split8(src + kt * 32, wxh[kt], wxl[kt]);
    }
    __syncthreads();

    const float*          aXf = L0 ? (const float*)xin_ + (size_t)brow * SS * DIN + 8 * g : nullptr;
    const unsigned short* aXb = L0 ? nullptr : (const unsigned short*)xin_ + (size_t)brow * SS * DIN + 8 * g;
    const unsigned short* bHb = WhhHi + nrow * WST + 8 * g;
    const unsigned short* bLb = WhhLo + nrow * WST + 8 * g;

    unsigned int* fbase = flags + (size_t)dir * SS * 64;   // per-direction flag plane

    const int batch = mi * 16 + 4 * g + p;   // this lane's epilogue batch
    // staging assignment: thread -> column-quad q (fixed), rows k0+2i
    const int q  = tid & 127;                // col quad 4q..4q+3
    const int k0 = tid >> 7;                 // 0 or 1
    const int prodjb = q >> 1;               // producer block owning this quad
    float creg = 0.f;

    for (int st = 0; st < SS; ++st) {
        const int t = dir ? (SS - 1 - st) : st;

        v4f acc0 = {0,0,0,0}, acc1 = {0,0,0,0}, acc2 = {0,0,0,0};
        v4f acc3 = {0,0,0,0}, acc4 = {0,0,0,0}, acc5 = {0,0,0,0};

        // ---- x-part (pre-poll; covers peers' publish latency) ----
        if (L0) {
            const float* aX = aXf + (size_t)t * DIN;
            #pragma unroll
            for (int kt = 0; kt < NKX; kt += 2) {
                v8s ah0, al0, ah1, al1;
                split8(aX + kt * 32, ah0, al0);
                split8(aX + (kt + 1) * 32, ah1, al1);
                acc0 = MFMA(ah0, wxh[kt],     acc0);
                acc1 = MFMA(ah1, wxh[kt + 1], acc1);
                acc2 = MFMA(ah0, wxl[kt],     acc2);
                acc3 = MFMA(ah1, wxl[kt + 1], acc3);
                acc4 = MFMA(al0, wxh[kt],     acc4);
                acc5 = MFMA(al1, wxh[kt + 1], acc5);
            }
        } else {
            const unsigned short* aX = aXb + (size_t)t * DIN;
            #pragma unroll
            for (int kt = 0; kt < NKX; kt += 2) {
                v8s a0 = *(const v8s*)(aX + kt * 32);
                v8s a1 = *(const v8s*)(aX + (kt + 1) * 32);
                acc0 = MFMA(a0, wxh[kt],     acc0);
                acc1 = MFMA(a1, wxh[kt + 1], acc1);
                acc2 = MFMA(a0, wxl[kt],     acc2);
                acc3 = MFMA(a1, wxl[kt + 1], acc3);
            }
        }

        // ---- fused poll+stage (bf16-hi packets, no unpack) ----
        if (st > 0) {
            {
                const unsigned int* f = fbase + (size_t)(st - 1) * 64 + prodjb;
                int guard = 0;
                while (!__hip_atomic_load(f, __ATOMIC_RELAXED,
                                          __HIP_MEMORY_SCOPE_AGENT)) {
                    __builtin_amdgcn_s_sleep(1);
                    if (++guard > (1 << 26)) break;   // anti-hang escape
                }
            }
            const u64t* hsrc = hrec + (size_t)(dir * 2 + ((st - 1) & 1)) * (BB * HH / 4);
            u64t vals[16];
            #pragma unroll
            for (int i = 0; i < 16; ++i)
                vals[i] = __hip_atomic_load(hsrc + ((size_t)(k0 + 2 * i) * (HH / 4)) + q,
                                            __ATOMIC_RELAXED, __HIP_MEMORY_SCOPE_AGENT);
            #pragma unroll
            for (int i = 0; i < 16; ++i)
                *(u64t*)(hHi + (k0 + 2 * i) * HST + 4 * q) = vals[i];   // bf16 layout-exact
            __syncthreads();

            const unsigned short* aHh = hHi + brow * HST + 8 * g;
            #pragma unroll
            for (int kt = 0; kt < NKH; kt += 2) {
                v8s ah0 = *(const v8s*)(aHh + kt * 32);
                v8s ah1 = *(const v8s*)(aHh + (kt + 1) * 32);
                v8s bh0 = *(const v8s*)(bHb + kt * 32);
                v8s bl0 = *(const v8s*)(bLb + kt * 32);
                v8s bh1 = *(const v8s*)(bHb + (kt + 1) * 32);
                v8s bl1 = *(const v8s*)(bLb + (kt + 1) * 32);
                acc0 = MFMA(ah0, bh0, acc0);
                acc1 = MFMA(ah1, bh1, acc1);
                acc2 = MFMA(ah0, bl0, acc2);
                acc3 = MFMA(ah1, bl1, acc3);
            }
        }
        acc0 = (acc0 + acc1) + (acc2 + acc3);
        if (L0) acc0 += (acc4 + acc5);

        // ---- in-wave 4x4 gate transpose (xor-1, xor-2 butterflies) ----
        float pi_, pf_, pg_, po_;
        {
            const float x0 = acc0[0], x1 = acc0[1], x2 = acc0[2], x3 = acc0[3];
            const float n0 = __shfl_xor(x0, 1), n1 = __shfl_xor(x1, 1);
            const float n2 = __shfl_xor(x2, 1), n3 = __shfl_xor(x3, 1);
            const float a0 = (p & 1) ? n1 : x0;
            const float a1 = (p & 1) ? x1 : n0;
            const float a2 = (p & 1) ? n3 : x2;
            const float a3 = (p & 1) ? x3 : n2;
            const float m0 = __shfl_xor(a0, 2), m1 = __shfl_xor(a1, 2);
            const float m2 = __shfl_xor(a2, 2), m3 = __shfl_xor(a3, 2);
            pi_ = (p & 2) ? m2 : a0;
            pf_ = (p & 2) ? m3 : a1;
            pg_ = (p & 2) ? a2 : m0;
            po_ = (p & 2) ? a3 : m1;
        }

        // ---- gates (torch order i,f,g,o) + state update + publish ----
        {
            const float ig = 1.f / (1.f + __expf(-(pi_ + bi_)));
            const float fg = 1.f / (1.f + __expf(-(pf_ + bf_)));
            const float gg = tanhf(pg_ + bg_);
            const float og = 1.f / (1.f + __expf(-(po_ + bo_)));
            creg = fg * creg + ig * gg;
            const float h = og * tanhf(creg);
            // gather the j-quad for packing (xor 4 -> jl^1, xor 8 -> jl^2)
            const float hq1 = __shfl_xor(h, 4);
            const float hq2 = __shfl_xor(h, 8);
            const float hq3 = __shfl_xor(hq1, 8);

            // 1) h-exchange: ONE u64 (4 bf16-hi) per (batch, j-quad)
            if ((jl & 3) == 0) {
                const u64t pk = (u64t)f2b(h)
                              | ((u64t)f2b(hq1) << 16)
                              | ((u64t)f2b(hq2) << 32)
                              | ((u64t)f2b(hq3) << 48);
                u64t* hw = hrec + (size_t)(dir * 2 + (st & 1)) * (BB * HH / 4)
                         + (size_t)batch * (HH / 4) + ((jbase + jl) >> 2);
                __hip_atomic_store(hw, pk, __ATOMIC_RELAXED, __HIP_MEMORY_SCOPE_AGENT);
            }
            // 2) drain vmem, 3) block barrier, 4) flag
            asm volatile("s_waitcnt vmcnt(0)" ::: "memory");
            __syncthreads();
            if (tid == 0)
                __hip_atomic_store(fbase + (size_t)st * 64 + jb, 1u,
                                   __ATOMIC_RELAXED, __HIP_MEMORY_SCOPE_AGENT);

            // 5) y output stores AFTER the flag (drain under next step's x-part)
            if (L0) {
                if ((jl & 1) == 0) {
                    const unsigned int pko = (unsigned int)f2b(h)
                                           | ((unsigned int)f2b(hq1) << 16);
                    *((unsigned int*)yout_ + (size_t)batch * SS * HH + (size_t)t * HH
                                           + dir * (HH / 2) + ((jbase + jl) >> 1)) = pko;
                }
            } else {
                ((float*)yout_)[((size_t)batch * SS + t) * (2 * HH) + dir * HH + jbase + jl] = h;
                if (st == SS - 1) {
                    hn[(dir * BB + batch) * HH + jbase + jl] = h;
                    cn[(dir * BB + batch) * HH + jbase + jl] = creg;
                }
            }
        }
    }
}

extern "C" void kernel_launch(void* const* d_in, const int* in_sizes, int n_in,
                              void* d_out, int out_size, void* d_ws, size_t ws_size,
                              hipStream_t stream) {
    (void)in_sizes; (void)n_in;

    const float* x      = (const float*)d_in[0];
    const float* Wih_f0 = (const float*)d_in[1];
    const float* Whh_f0 = (const float*)d_in[2];
    const float* b_f0   = (const float*)d_in[3];
    const float* Wih_b0 = (const float*)d_in[4];
    const float* Whh_b0 = (const float*)d_in[5];
    const float* b_b0   = (const float*)d_in[6];
    const float* Wih_f1 = (const float*)d_in[7];
    const float* Whh_f1 = (const float*)d_in[8];
    const float* b_f1   = (const float*)d_in[9];
    const float* Wih_b1 = (const float*)d_in[10];
    const float* Whh_b1 = (const float*)d_in[11];
    const float* b_b1   = (const float*)d_in[12];

    // ws: [0,32Mi) y0 bf16; +256K flags0[2][512][64]; +256K flags1; +128K hrec bf16-packed
    char* ws = (char*)d_ws;
    const size_t Y0B  = (size_t)BB * SS * 2 * HH * 2;             // 33,554,432
    const size_t FLG  = (size_t)2 * SS * 64 * 4;                  // 262,144 each
    const size_t HREC = (size_t)2 * 2 * BB * (HH / 4) * 8;        // 131,072
    const size_t NEED = Y0B + 2 * FLG + HREC;
    if (ws_size < NEED) return;
    if ((size_t)out_size < (size_t)BB * SS * 2 * HH + 4 * BB * HH) return;

    unsigned short* y0     = (unsigned short*)(ws);
    unsigned int*   flags0 = (unsigned int*)(ws + Y0B);
    unsigned int*   flags1 = (unsigned int*)(ws + Y0B + FLG);
    u64t*           hrec   = (u64t*)(ws + Y0B + 2 * FLG);         // shared (sequential kernels)

    float* out = (float*)d_out;                          // [B,S,2H] f32
    float* hn  = out + (size_t)BB * SS * 2 * HH;         // [2,B,H]
    float* cn  = hn + 2 * BB * HH;                       // [2,B,H]

    hipMemsetAsync(ws + Y0B, 0, 2 * FLG, stream);        // zero flags each call

    // LDS: Whh hi/lo (66,560) + hHi (33,280) = 99,840
    constexpr int SMB = 2 * WR * WST * 2 + BB * HST * 2;
    hipFuncSetAttribute(reinterpret_cast<const void*>(lstm_layer<512,  true>),
                        hipFuncAttributeMaxDynamicSharedMemorySize, SMB);
    hipFuncSetAttribute(reinterpret_cast<const void*>(lstm_layer<1024, false>),
                        hipFuncAttributeMaxDynamicSharedMemorySize, SMB);

    lstm_layer<512, true><<<128, 256, SMB, stream>>>(
        x, Wih_f0, Whh_f0, b_f0, Wih_b0, Whh_b0, b_b0,
        (void*)y0, hrec, flags0, nullptr, nullptr);

    lstm_layer<1024, false><<<128, 256, SMB, stream>>>(
        y0, Wih_f1, Whh_f1, b_f1, Wih_b1, Whh_b1, b_b1,
        (void*)out, hrec, flags1, hn, cn);
}